// Round 1
// baseline (212.429 us; speedup 1.0000x reference)
//
#include <hip/hip_runtime.h>
#include <cfloat>

#define B_ 64
#define S_ 64
#define F_ 512
#define E_ 1024
#define D_ 1024

// ---------------------------------------------------------------------------
// Kernel 1: s_ftr[b,f] = dot(features[b,f,:], W_f)  for rows with f < len[b].
// One wave (64 lanes) per row; 4 x float4 per lane = 1024 floats per row.
// ---------------------------------------------------------------------------
__global__ __launch_bounds__(256) void k_rowdot(const float* __restrict__ features,
                                                const float* __restrict__ W_f,
                                                const int* __restrict__ lens,
                                                float* __restrict__ s_ftr) {
    const int wave = threadIdx.x >> 6;
    const int lane = threadIdx.x & 63;
    const int row  = blockIdx.x * 4 + wave;      // row in [0, B_*F_)
    const int b    = row >> 9;                   // row / F_
    const int f    = row & (F_ - 1);             // row % F_
    if (f >= lens[b]) return;                    // masked row: never read it

    const float4* fp = reinterpret_cast<const float4*>(features + (size_t)row * D_);
    const float4* wp = reinterpret_cast<const float4*>(W_f);
    float acc = 0.f;
#pragma unroll
    for (int j = 0; j < 4; ++j) {
        const float4 v = fp[lane + 64 * j];
        const float4 w = wp[lane + 64 * j];
        acc = fmaf(v.x, w.x, acc);
        acc = fmaf(v.y, w.y, acc);
        acc = fmaf(v.z, w.z, acc);
        acc = fmaf(v.w, w.w, acc);
    }
#pragma unroll
    for (int off = 32; off; off >>= 1) acc += __shfl_xor(acc, off, 64);
    if (lane == 0) s_ftr[row] = acc;
}

// ---------------------------------------------------------------------------
// Kernel 2: p[b,f] = softmax_f(s_ftr[b, 0..len)) with masked tail = 0.
// One block of 512 threads per b.
// ---------------------------------------------------------------------------
__global__ __launch_bounds__(512) void k_softmax(const float* __restrict__ s_ftr,
                                                 const int* __restrict__ lens,
                                                 float* __restrict__ p) {
    __shared__ float red[8];
    const int b    = blockIdx.x;
    const int f    = threadIdx.x;
    const int len  = lens[b];
    const int wave = threadIdx.x >> 6;
    const int lane = threadIdx.x & 63;

    float v = (f < len) ? s_ftr[b * F_ + f] : -FLT_MAX;

    // block max
    float m = v;
#pragma unroll
    for (int off = 32; off; off >>= 1) m = fmaxf(m, __shfl_xor(m, off, 64));
    if (lane == 0) red[wave] = m;
    __syncthreads();
    float m8 = red[0];
#pragma unroll
    for (int i = 1; i < 8; ++i) m8 = fmaxf(m8, red[i]);

    const float e = (f < len) ? __expf(v - m8) : 0.f;

    // block sum
    float s = e;
#pragma unroll
    for (int off = 32; off; off >>= 1) s += __shfl_xor(s, off, 64);
    __syncthreads();
    if (lane == 0) red[wave] = s;
    __syncthreads();
    float s8 = 0.f;
#pragma unroll
    for (int i = 0; i < 8; ++i) s8 += red[i];

    p[b * F_ + f] = e / s8;
}

// ---------------------------------------------------------------------------
// Kernel 3: ctx[b,d] = sum_{f<len} p[b,f] * features[b,f,d], then broadcast
// to out[b, 0..S_, d].  Grid: (D_/256, B_), 256 threads, thread owns one d.
// ---------------------------------------------------------------------------
__global__ __launch_bounds__(256) void k_ctx(const float* __restrict__ features,
                                             const float* __restrict__ p,
                                             const int* __restrict__ lens,
                                             float* __restrict__ out) {
    __shared__ float sp[F_];
    const int b   = blockIdx.y;
    const int d   = blockIdx.x * 256 + threadIdx.x;
    const int len = lens[b];

    for (int i = threadIdx.x; i < F_; i += 256) sp[i] = p[b * F_ + i];
    __syncthreads();

    const float* fb = features + (size_t)b * F_ * D_ + d;
    float acc = 0.f;
    int f = 0;
    for (; f + 8 <= len; f += 8) {
        const float a0 = fb[(size_t)(f + 0) * D_];
        const float a1 = fb[(size_t)(f + 1) * D_];
        const float a2 = fb[(size_t)(f + 2) * D_];
        const float a3 = fb[(size_t)(f + 3) * D_];
        const float a4 = fb[(size_t)(f + 4) * D_];
        const float a5 = fb[(size_t)(f + 5) * D_];
        const float a6 = fb[(size_t)(f + 6) * D_];
        const float a7 = fb[(size_t)(f + 7) * D_];
        acc = fmaf(sp[f + 0], a0, acc);
        acc = fmaf(sp[f + 1], a1, acc);
        acc = fmaf(sp[f + 2], a2, acc);
        acc = fmaf(sp[f + 3], a3, acc);
        acc = fmaf(sp[f + 4], a4, acc);
        acc = fmaf(sp[f + 5], a5, acc);
        acc = fmaf(sp[f + 6], a6, acc);
        acc = fmaf(sp[f + 7], a7, acc);
    }
    for (; f < len; ++f) acc = fmaf(sp[f], fb[(size_t)f * D_], acc);

    float* ob = out + (size_t)b * S_ * D_ + d;
#pragma unroll
    for (int s = 0; s < S_; ++s) ob[(size_t)s * D_] = acc;
}

// ---------------------------------------------------------------------------
extern "C" void kernel_launch(void* const* d_in, const int* in_sizes, int n_in,
                              void* d_out, int out_size, void* d_ws, size_t ws_size,
                              hipStream_t stream) {
    (void)in_sizes; (void)n_in; (void)out_size; (void)ws_size;
    // Inputs (setup_inputs order): sen_emb, features, feature_lens, W, b
    // sen_emb and b are mathematically irrelevant: softmax over f is invariant
    // to the per-(b,s) additive constant  s_emb[b,s] + b0.
    const float* features = (const float*)d_in[1];
    const int*   lens     = (const int*)d_in[2];
    const float* W        = (const float*)d_in[3];
    float*       out      = (float*)d_out;

    float* s_ftr = (float*)d_ws;            // B_*F_ floats (128 KB)
    float* p     = s_ftr + B_ * F_;         // B_*F_ floats (128 KB)

    k_rowdot <<<dim3(B_ * F_ / 4), 256, 0, stream>>>(features, W + E_, lens, s_ftr);
    k_softmax<<<dim3(B_),          512, 0, stream>>>(s_ftr, lens, p);
    k_ctx    <<<dim3(D_ / 256, B_), 256, 0, stream>>>(features, p, lens, out);
}

// Round 2
// 209.529 us; speedup vs baseline: 1.0138x; 1.0138x over previous
//
#include <hip/hip_runtime.h>
#include <cfloat>

#define B_ 64
#define S_ 64
#define F_ 512
#define E_ 1024
#define D_ 1024
#define FT_ 32           // f-rows per ctx tile
#define NT_ (F_ / FT_)   // 16 tiles

// ---------------------------------------------------------------------------
// Kernel 1: s_ftr[b,f] = dot(features[b,f,:], W_f) for rows with f < len[b].
// One wave per row, 4x float4 per lane (64 lanes * 16 floats = 1024).
// ---------------------------------------------------------------------------
__global__ __launch_bounds__(256) void k_rowdot(const float* __restrict__ features,
                                                const float* __restrict__ W_f,
                                                const int* __restrict__ lens,
                                                float* __restrict__ s_ftr) {
    const int wave = threadIdx.x >> 6;
    const int lane = threadIdx.x & 63;
    const int row  = blockIdx.x * 4 + wave;
    const int b    = row >> 9;
    const int f    = row & (F_ - 1);
    if (f >= lens[b]) return;                    // masked row: never read

    const float4* fp = reinterpret_cast<const float4*>(features + (size_t)row * D_);
    const float4* wp = reinterpret_cast<const float4*>(W_f);
    float acc = 0.f;
#pragma unroll
    for (int j = 0; j < 4; ++j) {
        const float4 v = fp[lane + 64 * j];
        const float4 w = wp[lane + 64 * j];
        acc = fmaf(v.x, w.x, acc);
        acc = fmaf(v.y, w.y, acc);
        acc = fmaf(v.z, w.z, acc);
        acc = fmaf(v.w, w.w, acc);
    }
#pragma unroll
    for (int off = 32; off; off >>= 1) acc += __shfl_xor(acc, off, 64);
    if (lane == 0) s_ftr[row] = acc;
}

// ---------------------------------------------------------------------------
// Kernel 2: per (b, tile): inline softmax over s_ftr[b,:len], then
// part[b,tile,d] = sum_{f in tile} p[b,f] * features[b,f,d].
// 256 threads; thread t owns d = 4t..4t+3 (one float4). Row reads are fully
// coalesced: 256 threads x 16 B = the whole 4 KB row per f-iteration.
// ---------------------------------------------------------------------------
__global__ __launch_bounds__(256) void k_ctx_part(const float* __restrict__ features,
                                                  const float* __restrict__ s_ftr,
                                                  const int* __restrict__ lens,
                                                  float* __restrict__ part) {
    const int b    = blockIdx.y;
    const int tile = blockIdx.x;
    const int len  = lens[b];
    const int f0   = tile * FT_;
    if (f0 >= len) return;                       // tile fully masked

    __shared__ float sw[F_];                     // softmax weights
    __shared__ float red_m[4], red_s[4];
    const int t    = threadIdx.x;
    const int wave = t >> 6;
    const int lane = t & 63;

    // ---- softmax over the full row (each block recomputes it; ~1K exp) ----
    const float v0 = (t       < len) ? s_ftr[b * F_ + t]       : -FLT_MAX;
    const float v1 = (t + 256 < len) ? s_ftr[b * F_ + t + 256] : -FLT_MAX;
    float m = fmaxf(v0, v1);
#pragma unroll
    for (int off = 32; off; off >>= 1) m = fmaxf(m, __shfl_xor(m, off, 64));
    if (lane == 0) red_m[wave] = m;
    __syncthreads();
    const float m4 = fmaxf(fmaxf(red_m[0], red_m[1]), fmaxf(red_m[2], red_m[3]));

    const float e0 = (t       < len) ? __expf(v0 - m4) : 0.f;
    const float e1 = (t + 256 < len) ? __expf(v1 - m4) : 0.f;
    float s = e0 + e1;
#pragma unroll
    for (int off = 32; off; off >>= 1) s += __shfl_xor(s, off, 64);
    if (lane == 0) red_s[wave] = s;
    __syncthreads();
    const float inv = 1.f / (red_s[0] + red_s[1] + red_s[2] + red_s[3]);
    sw[t]       = e0 * inv;
    sw[t + 256] = e1 * inv;
    __syncthreads();

    // ---- weighted accumulation over this tile's rows ----
    const float4* fb = reinterpret_cast<const float4*>(features + ((size_t)b * F_ + f0) * D_);
    float4 acc = make_float4(0.f, 0.f, 0.f, 0.f);
    const int nf = min(FT_, len - f0);
    for (int f = 0; f < nf; ++f) {
        const float  w = sw[f0 + f];             // LDS broadcast (free)
        const float4 v = fb[f * 256 + t];
        acc.x = fmaf(w, v.x, acc.x);
        acc.y = fmaf(w, v.y, acc.y);
        acc.z = fmaf(w, v.z, acc.z);
        acc.w = fmaf(w, v.w, acc.w);
    }
    reinterpret_cast<float4*>(part)[((size_t)b * NT_ + tile) * 256 + t] = acc;
}

// ---------------------------------------------------------------------------
// Kernel 3: ctx[b,d] = sum over valid tiles of part[b,t,d]; broadcast to
// out[b, s0..s0+8, d].  Grid (8, B): each block writes 8 s-rows.
// ---------------------------------------------------------------------------
__global__ __launch_bounds__(256) void k_bcast(const float* __restrict__ part,
                                               const int* __restrict__ lens,
                                               float* __restrict__ out) {
    const int b  = blockIdx.y;
    const int t  = threadIdx.x;                  // quad index: d = 4t..4t+3
    const int nt = min(NT_, (lens[b] + FT_ - 1) / FT_);

    const float4* pp = reinterpret_cast<const float4*>(part) + (size_t)b * NT_ * 256 + t;
    float4 acc = make_float4(0.f, 0.f, 0.f, 0.f);
    for (int k = 0; k < nt; ++k) {
        const float4 v = pp[(size_t)k * 256];
        acc.x += v.x; acc.y += v.y; acc.z += v.z; acc.w += v.w;
    }

    const int s0 = blockIdx.x * 8;
    float4* ob = reinterpret_cast<float4*>(out) + ((size_t)b * S_ + s0) * 256 + t;
#pragma unroll
    for (int s = 0; s < 8; ++s) ob[(size_t)s * 256] = acc;
}

// ---------------------------------------------------------------------------
extern "C" void kernel_launch(void* const* d_in, const int* in_sizes, int n_in,
                              void* d_out, int out_size, void* d_ws, size_t ws_size,
                              hipStream_t stream) {
    (void)in_sizes; (void)n_in; (void)out_size; (void)ws_size;
    // Inputs: sen_emb, features, feature_lens, W, b.
    // sen_emb and b are mathematically irrelevant: softmax over f is invariant
    // to the per-(b,s) additive constant s_emb[b,s] + b0, so attn (and the
    // output) is independent of s -> compute one ctx row per b, broadcast.
    const float* features = (const float*)d_in[1];
    const int*   lens     = (const int*)d_in[2];
    const float* W        = (const float*)d_in[3];
    float*       out      = (float*)d_out;

    float* s_ftr = (float*)d_ws;                 // B_*F_ floats   (128 KB)
    float* part  = s_ftr + B_ * F_;              // B_*NT_*D_ floats (4 MB)

    k_rowdot  <<<dim3(B_ * F_ / 4), 256, 0, stream>>>(features, W + E_, lens, s_ftr);
    k_ctx_part<<<dim3(NT_, B_),     256, 0, stream>>>(features, s_ftr, lens, part);
    k_bcast   <<<dim3(8, B_),       256, 0, stream>>>(part, lens, out);
}